// Round 7
// baseline (1048.882 us; speedup 1.0000x reference)
//
#include <hip/hip_runtime.h>
#include <stdint.h>

// GCN 2-layer: h1 = relu(Anorm @ (x@W1) + b1); out = Anorm @ (h1@W2) + b2
// R7: revert gemm1 to R4 frame (48KB LDS, 2 blocks/CU) + A register pipeline
//     one iter ahead (two static reg sets) so STOREA never waits vmcnt;
//     all VMEM issued before the MFMA cluster. k_scan keeps dinv fold.

namespace {
constexpr int NN = 16384;     // nodes
constexpr int CH = 256;       // hidden channels
constexpr int KC = 16;        // classes
constexpr int NE = 524288;    // edges
constexpr int KD = 16384;     // input feature dim
constexpr int KSPLIT = 4;
constexpr int BM = 128;
constexpr int NT = KD / KSPLIT / 32;   // 128

// workspace byte offsets
constexpr size_t OFF_W1T  = 0;            // bf16 [256][16384]        = 8 MiB
constexpr size_t OFF_HP   = 8388608;      // f32  [4][16384][256]     = 64 MiB
constexpr size_t OFF_HB   = 75497472;     // bf16 [16384][256]        = 8 MiB
constexpr size_t OFF_OUT1 = 83886080;     // f32  [16384][256]        = 16 MiB
constexpr size_t OFF_H2   = 100663296;    // f32  [16384][16]         = 1 MiB
constexpr size_t OFF_DEG  = 101711872;    // f32  [16384]
constexpr size_t OFF_CNT  = 101777408;    // i32  [16384] (contiguous w/ DEG)
constexpr size_t OFF_DINV = 101842944;    // f32  [16384]
constexpr size_t OFF_ROWP = 101908480;    // i32  [16385]
constexpr size_t OFF_CUR  = 102039552;    // i32  [16384]
constexpr size_t OFF_COLS = 102105088;    // i32  [E] = 2 MiB
constexpr size_t OFF_NRM  = 104202240;    // f32  [E] = 2 MiB
}

typedef __attribute__((ext_vector_type(8))) short bf16x8;
typedef __attribute__((ext_vector_type(4))) float f32x4;

__device__ __forceinline__ unsigned short f2bf(float f) {
  unsigned int u = __builtin_bit_cast(unsigned int, f);
  u += 0x7fffu + ((u >> 16) & 1u);
  return (unsigned short)(u >> 16);
}
__device__ __forceinline__ float bf2f(unsigned short v) {
  unsigned int u = ((unsigned int)v) << 16;
  return __builtin_bit_cast(float, u);
}

// ---- W1 [16384][256] f32  ->  W1T [256][16384] bf16 ----
__global__ __launch_bounds__(256)
void k_w1t(const float* __restrict__ w1, unsigned short* __restrict__ w1t) {
  __shared__ float tile[64][65];
  const int t = threadIdx.x;
  const int kb = blockIdx.x * 64;
  const int nb = blockIdx.y * 64;
  const int r = t >> 6;
  const int c = t & 63;
#pragma unroll
  for (int i = 0; i < 16; ++i)
    tile[i * 4 + r][c] = w1[(size_t)(kb + i * 4 + r) * CH + nb + c];
  __syncthreads();
#pragma unroll
  for (int i = 0; i < 16; ++i)
    w1t[(size_t)(nb + i * 4 + r) * KD + kb + c] = f2bf(tile[c][i * 4 + r]);
}

// ---- degree + in-edge histogram ----
__global__ __launch_bounds__(256)
void k_deg(const int* __restrict__ dst, const float* __restrict__ ew,
           float* __restrict__ deg, int* __restrict__ cnt) {
  const int e = blockIdx.x * 256 + threadIdx.x;
  const int d = dst[e];
  atomicAdd(&deg[d], ew[e]);
  atomicAdd(&cnt[d], 1);
}

// ---- exclusive scan of cnt -> rowp/cursor, plus dinv (single block) ----
__global__ __launch_bounds__(256)
void k_scan(const int* __restrict__ cnt, const float* __restrict__ deg,
            int* __restrict__ rowp, int* __restrict__ curs,
            float* __restrict__ dinv) {
  __shared__ int ps[256];
  const int t = threadIdx.x;
  const int base = t * 64;
  int s = 0;
  for (int j = 0; j < 64; ++j) s += cnt[base + j];
  ps[t] = s;
  for (int j = 0; j < 64; ++j)
    dinv[base + j] = rsqrtf(deg[base + j] + 1.0f);   // +1 = self-loop weight
  __syncthreads();
  int v = s;
  for (int off = 1; off < 256; off <<= 1) {
    int u = (t >= off) ? ps[t - off] : 0;
    __syncthreads();
    v += u;
    ps[t] = v;
    __syncthreads();
  }
  int run = v - s;
  for (int j = 0; j < 64; ++j) {
    int c = cnt[base + j];
    rowp[base + j] = run;
    curs[base + j] = run;
    run += c;
  }
  if (t == 255) rowp[NN] = run;
}

// ---- CSR fill: edge -> (src, norm) bucketed by dst ----
__global__ __launch_bounds__(256)
void k_fill(const int* __restrict__ src, const int* __restrict__ dst,
            const float* __restrict__ ew, const float* __restrict__ dinv,
            int* __restrict__ curs, int* __restrict__ cols, float* __restrict__ nrm) {
  const int e = blockIdx.x * 256 + threadIdx.x;
  const int s = src[e], d = dst[e];
  const int pos = atomicAdd(&curs[d], 1);
  cols[pos] = s;
  nrm[pos] = dinv[s] * ew[e] * dinv[d];
}

// ---- GEMM1: hp[kb][16384][256] = x[:, kb-quarter] @ W1T[kb-quarter] ----
// BM=128 BN=256 BK=32, KSPLIT=4, grid 512, 2 blocks/CU (48KB LDS).
// A reg-pipelined one iter ahead: STOREA consumes loads issued last iter
// (drained by last barrier) -> no vmcnt wait. VMEM all issued pre-MFMA.
__global__ __launch_bounds__(256, 2)
void k_gemm1(const float* __restrict__ x, const unsigned short* __restrict__ w1t,
             float* __restrict__ hp) {
  __shared__ __align__(16) unsigned short As[2][BM * 32];    // 8 KB each
  __shared__ __align__(16) unsigned short Bs[2][256 * 32];   // 16 KB each

  const int tid  = threadIdx.x;
  const int lane = tid & 63;
  const int wave = tid >> 6;

  const int bid  = blockIdx.x;
  const int xcd  = bid & 7;
  const int slot = bid >> 3;                   // 0..63
  const int kb   = xcd >> 1;                   // 0..3, constant per XCD
  const int bm0  = (slot * 2 + (xcd & 1)) * BM;
  const int koff = kb * (KD / KSPLIT);
  const int wn0  = wave * 64;

  // A staging coords: thread -> rows r0, r0+64, k-chunk kq, XOR chunk swizzle
  const int r0  = tid >> 2;
  const int kq  = tid & 3;
  const int acn = kq ^ ((r0 >> 1) & 3);
  const int aoff0 = r0 * 32 + acn * 8;
  const int aoff1 = (r0 + 64) * 32 + acn * 8;

  // B async staging: linear LDS dest, pre-swizzled global source
  const int cc = (lane & 3) ^ ((lane >> 3) & 3);
  const unsigned short* bbase =
      w1t + (size_t)(wave * 64 + (lane >> 2)) * KD + koff + cc * 8;

  // fragment-read coords
  const int fr = lane & 15, fg = lane >> 4;
  const int fch = fg ^ ((fr >> 1) & 3);
  const int fA = fr * 32 + fch * 8;
  const int fB = (wn0 + fr) * 32 + fch * 8;

  const float* xrow0 = x + (size_t)(bm0 + r0) * KD + koff + kq * 8;
  const float* xrow1 = xrow0 + (size_t)64 * KD;

  f32x4 acc[8][4] = {};

  // two static A reg sets (rule #20: no runtime-indexed reg arrays)
  float4 sa0, sa1, sa2, sa3;   // set A
  float4 sb0, sb1, sb2, sb3;   // set B

  auto LOADA = [&](int t, float4& v0, float4& v1, float4& v2, float4& v3) {
    const float* p0 = xrow0 + (size_t)t * 32;
    const float* p1 = xrow1 + (size_t)t * 32;
    v0 = *reinterpret_cast<const float4*>(p0);
    v1 = *reinterpret_cast<const float4*>(p0 + 4);
    v2 = *reinterpret_cast<const float4*>(p1);
    v3 = *reinterpret_cast<const float4*>(p1 + 4);
  };
  auto STOREA = [&](int buf, const float4& v0, const float4& v1,
                    const float4& v2, const float4& v3) {
    bf16x8 v;
    v[0] = (short)f2bf(v0.x); v[1] = (short)f2bf(v0.y);
    v[2] = (short)f2bf(v0.z); v[3] = (short)f2bf(v0.w);
    v[4] = (short)f2bf(v1.x); v[5] = (short)f2bf(v1.y);
    v[6] = (short)f2bf(v1.z); v[7] = (short)f2bf(v1.w);
    *reinterpret_cast<bf16x8*>(&As[buf][aoff0]) = v;
    v[0] = (short)f2bf(v2.x); v[1] = (short)f2bf(v2.y);
    v[2] = (short)f2bf(v2.z); v[3] = (short)f2bf(v2.w);
    v[4] = (short)f2bf(v3.x); v[5] = (short)f2bf(v3.y);
    v[6] = (short)f2bf(v3.z); v[7] = (short)f2bf(v3.w);
    *reinterpret_cast<bf16x8*>(&As[buf][aoff1]) = v;
  };
  auto GLOADB = [&](int t, int buf) {
    const unsigned short* g = bbase + (size_t)t * 32;
#pragma unroll
    for (int i = 0; i < 4; ++i) {
      __builtin_amdgcn_global_load_lds(
          (const __attribute__((address_space(1))) void*)(g + (size_t)i * 16 * KD),
          (__attribute__((address_space(3))) void*)(&Bs[buf][(wave * 64 + i * 16) * 32]),
          16, 0, 0);
    }
  };
  auto COMPUTE = [&](int t) {
    const int cur = t & 1;
    bf16x8 bfr[4];
#pragma unroll
    for (int ni = 0; ni < 4; ++ni)
      bfr[ni] = *reinterpret_cast<const bf16x8*>(&Bs[cur][fB + ni * 512]);
    __builtin_amdgcn_s_setprio(1);
#pragma unroll
    for (int mi = 0; mi < 8; ++mi) {
      const bf16x8 af = *reinterpret_cast<const bf16x8*>(&As[cur][fA + mi * 512]);
#pragma unroll
      for (int ni = 0; ni < 4; ++ni)
        acc[mi][ni] = __builtin_amdgcn_mfma_f32_16x16x32_bf16(af, bfr[ni], acc[mi][ni], 0, 0, 0);
    }
    __builtin_amdgcn_s_setprio(0);
  };

  // prologue: tile0 staged; tile1 loaded into SB (drained by first barrier)
  LOADA(0, sa0, sa1, sa2, sa3);
  STOREA(0, sa0, sa1, sa2, sa3);   // one-time vmcnt wait
  GLOADB(0, 0);
  LOADA(1, sb0, sb1, sb2, sb3);
  __syncthreads();

  for (int t = 0; t < NT; t += 2) {
    {  // even iter: consume SB (tile t+1), refill SA (tile t+2)
      STOREA((t + 1) & 1, sb0, sb1, sb2, sb3);   // no wait: loads drained
      if (t + 2 < NT) LOADA(t + 2, sa0, sa1, sa2, sa3);
      GLOADB(t + 1, (t + 1) & 1);
      COMPUTE(t);
      __syncthreads();
    }
    {  // odd iter t+1: consume SA (tile t+2), refill SB (tile t+3)
      const int u = t + 1;
      if (u + 1 < NT) {
        STOREA((u + 1) & 1, sa0, sa1, sa2, sa3);
        if (u + 2 < NT) LOADA(u + 2, sb0, sb1, sb2, sb3);
        GLOADB(u + 1, (u + 1) & 1);
        COMPUTE(u);
        __syncthreads();
      } else {
        COMPUTE(u);   // last iter: no staging, no barrier
      }
    }
  }

  float* hpo = hp + (size_t)kb * NN * CH;
#pragma unroll
  for (int mi = 0; mi < 8; ++mi)
#pragma unroll
    for (int ni = 0; ni < 4; ++ni)
#pragma unroll
      for (int r = 0; r < 4; ++r) {
        const int m = bm0 + mi * 16 + fg * 4 + r;
        const int n = wn0 + ni * 16 + fr;
        hpo[(size_t)m * CH + n] = acc[mi][ni][r];
      }
}

// ---- reduce 4 partials -> h bf16 ----
__global__ __launch_bounds__(256)
void k_hred(const float* __restrict__ hp, unsigned short* __restrict__ hb) {
  const size_t i = ((size_t)blockIdx.x * 256 + threadIdx.x) * 8;
  float s[8];
#pragma unroll
  for (int j = 0; j < 8; ++j) s[j] = 0.f;
#pragma unroll
  for (int p = 0; p < KSPLIT; ++p) {
    const float* q = hp + (size_t)p * NN * CH + i;
    const float4 v0 = *reinterpret_cast<const float4*>(q);
    const float4 v1 = *reinterpret_cast<const float4*>(q + 4);
    s[0] += v0.x; s[1] += v0.y; s[2] += v0.z; s[3] += v0.w;
    s[4] += v1.x; s[5] += v1.y; s[6] += v1.z; s[7] += v1.w;
  }
  bf16x8 o;
#pragma unroll
  for (int j = 0; j < 8; ++j) o[j] = (short)f2bf(s[j]);
  *reinterpret_cast<bf16x8*>(hb + i) = o;
}

// ---- aggregation 1 (+b1, relu): wave-parallel edges, lane owns 4 channels ----
__global__ __launch_bounds__(256)
void k_agg1(const unsigned short* __restrict__ hb, const int* __restrict__ rowp,
            const int* __restrict__ cols, const float* __restrict__ nrm,
            const float* __restrict__ dinv, const float* __restrict__ b1,
            float* __restrict__ out1) {
  __shared__ float red[4][256];
  const int i = blockIdx.x;
  const int t = threadIdx.x;
  const int w = t >> 6, l = t & 63;
  const int beg = rowp[i], end = rowp[i + 1];
  float a0 = 0.f, a1 = 0.f, a2 = 0.f, a3 = 0.f;
  int e = beg + w;
  for (; e + 4 < end; e += 8) {
    const int s0 = cols[e], s1 = cols[e + 4];
    const float n0 = nrm[e], n1 = nrm[e + 4];
    const ushort4 h0 = *reinterpret_cast<const ushort4*>(hb + (size_t)s0 * CH + l * 4);
    const ushort4 h1 = *reinterpret_cast<const ushort4*>(hb + (size_t)s1 * CH + l * 4);
    a0 += n0 * bf2f(h0.x) + n1 * bf2f(h1.x);
    a1 += n0 * bf2f(h0.y) + n1 * bf2f(h1.y);
    a2 += n0 * bf2f(h0.z) + n1 * bf2f(h1.z);
    a3 += n0 * bf2f(h0.w) + n1 * bf2f(h1.w);
  }
  if (e < end) {
    const int s0 = cols[e];
    const float n0 = nrm[e];
    const ushort4 h0 = *reinterpret_cast<const ushort4*>(hb + (size_t)s0 * CH + l * 4);
    a0 += n0 * bf2f(h0.x); a1 += n0 * bf2f(h0.y);
    a2 += n0 * bf2f(h0.z); a3 += n0 * bf2f(h0.w);
  }
  *reinterpret_cast<float4*>(&red[w][l * 4]) = make_float4(a0, a1, a2, a3);
  __syncthreads();
  const float di = dinv[i];
  float sum = red[0][t] + red[1][t] + red[2][t] + red[3][t]
            + di * di * bf2f(hb[(size_t)i * CH + t]) + b1[t];
  out1[(size_t)i * CH + t] = fmaxf(sum, 0.0f);
}

// ---- GEMM2: h2[16384][16] = out1 @ W2[256][16] ----
__global__ __launch_bounds__(256)
void k_gemm2(const float* __restrict__ out1, const float* __restrict__ w2,
             float* __restrict__ h2) {
  __shared__ float xs[16][256];
  __shared__ float ws[256 * 16];
  const int t = threadIdx.x;
  const int n0 = blockIdx.x * 16;
#pragma unroll
  for (int i = 0; i < 16; ++i) ws[i * 256 + t] = w2[i * 256 + t];
#pragma unroll
  for (int i = 0; i < 16; ++i) xs[i][t] = out1[(size_t)(n0 + i) * CH + t];
  __syncthreads();
  const int node = t >> 4, k = t & 15;
  float acc = 0.f;
#pragma unroll 8
  for (int c = 0; c < 256; ++c) acc += xs[node][c] * ws[c * 16 + k];
  h2[(size_t)(n0 + node) * KC + k] = acc;
}

// ---- aggregation 2 (+b2): one wave per node ----
__global__ __launch_bounds__(256)
void k_agg2(const float* __restrict__ h2, const int* __restrict__ rowp,
            const int* __restrict__ cols, const float* __restrict__ nrm,
            const float* __restrict__ dinv, const float* __restrict__ b2,
            float* __restrict__ out) {
  const int i = blockIdx.x * 4 + (threadIdx.x >> 6);
  const int lane = threadIdx.x & 63;
  const int k = lane & 15, g = lane >> 4;
  const int beg = rowp[i], end = rowp[i + 1];
  float acc = 0.f;
  for (int e = beg + g; e < end; e += 4)
    acc += nrm[e] * h2[(size_t)cols[e] * KC + k];
  acc += __shfl_xor(acc, 16);
  acc += __shfl_xor(acc, 32);
  if (g == 0) {
    const float di = dinv[i];
    out[(size_t)i * KC + k] = acc + di * di * h2[(size_t)i * KC + k] + b2[k];
  }
}

extern "C" void kernel_launch(void* const* d_in, const int* in_sizes, int n_in,
                              void* d_out, int out_size, void* d_ws, size_t ws_size,
                              hipStream_t stream) {
  const float* x  = (const float*)d_in[0];
  const int*   ei = (const int*)d_in[1];
  const float* ew = (const float*)d_in[2];
  const float* w1 = (const float*)d_in[3];
  const float* b1 = (const float*)d_in[4];
  const float* w2 = (const float*)d_in[5];
  const float* b2 = (const float*)d_in[6];
  const int* src = ei;
  const int* dst = ei + NE;

  uint8_t* ws = (uint8_t*)d_ws;
  unsigned short* w1t = (unsigned short*)(ws + OFF_W1T);
  float* hp   = (float*)(ws + OFF_HP);
  unsigned short* hb = (unsigned short*)(ws + OFF_HB);
  float* out1 = (float*)(ws + OFF_OUT1);
  float* h2   = (float*)(ws + OFF_H2);
  float* deg  = (float*)(ws + OFF_DEG);
  int*   cnt  = (int*)(ws + OFF_CNT);
  float* dinv = (float*)(ws + OFF_DINV);
  int*   rowp = (int*)(ws + OFF_ROWP);
  int*   curs = (int*)(ws + OFF_CUR);
  int*   cols = (int*)(ws + OFF_COLS);
  float* nrm  = (float*)(ws + OFF_NRM);
  float* out  = (float*)d_out;

  hipMemsetAsync(ws + OFF_DEG, 0, 131072, stream);  // deg + cnt

  k_w1t <<<dim3(256, 4), 256, 0, stream>>>(w1, w1t);
  k_deg <<<NE / 256, 256, 0, stream>>>(dst, ew, deg, cnt);
  k_scan<<<1, 256, 0, stream>>>(cnt, deg, rowp, curs, dinv);
  k_fill<<<NE / 256, 256, 0, stream>>>(src, dst, ew, dinv, curs, cols, nrm);
  k_gemm1<<<(NN / BM) * KSPLIT, 256, 0, stream>>>(x, w1t, hp);
  k_hred<<<NN * CH / (256 * 8), 256, 0, stream>>>(hp, hb);
  k_agg1<<<NN, 256, 0, stream>>>(hb, rowp, cols, nrm, dinv, b1, out1);
  k_gemm2<<<NN / 16, 256, 0, stream>>>(out1, w2, h2);
  k_agg2<<<NN / 4, 256, 0, stream>>>(h2, rowp, cols, nrm, dinv, b2, out);
}

// Round 8
// 481.091 us; speedup vs baseline: 2.1802x; 2.1802x over previous
//
#include <hip/hip_runtime.h>
#include <stdint.h>

// GCN 2-layer: h1 = relu(Anorm @ (x@W1) + b1); out = Anorm @ (h1@W2) + b2
// R8: gemm1 redesigned for DRAM row locality: BM=64, outer BK=256, each A
//     wave-instruction reads 1 KB contiguous of one row (16 float4/thread in
//     regs), cvt->bf16 into swizzled As at outer boundary. B via glds into
//     TRIPLE-buffered Bs with uniform counted vmcnt(4) (issues after barrier).
//     acc=64 AGPR so VGPR+AGPR fits the 256 unified cap (R7 spill lesson).

namespace {
constexpr int NN = 16384;     // nodes
constexpr int CH = 256;       // hidden channels
constexpr int KC = 16;        // classes
constexpr int NE = 524288;    // edges
constexpr int KD = 16384;     // input feature dim
constexpr int KSPLIT = 4;
constexpr int BM = 64;
constexpr int NOUT = KD / KSPLIT / 256;   // 16 outer iters
constexpr int BOFF = 32768;               // Bs region base in smem

// workspace byte offsets
constexpr size_t OFF_W1T  = 0;            // bf16 [256][16384]        = 8 MiB
constexpr size_t OFF_HP   = 8388608;      // f32  [4][16384][256]     = 64 MiB
constexpr size_t OFF_HB   = 75497472;     // bf16 [16384][256]        = 8 MiB
constexpr size_t OFF_OUT1 = 83886080;     // f32  [16384][256]        = 16 MiB
constexpr size_t OFF_H2   = 100663296;    // f32  [16384][16]         = 1 MiB
constexpr size_t OFF_DEG  = 101711872;    // f32  [16384]
constexpr size_t OFF_CNT  = 101777408;    // i32  [16384] (contiguous w/ DEG)
constexpr size_t OFF_DINV = 101842944;    // f32  [16384]
constexpr size_t OFF_ROWP = 101908480;    // i32  [16385]
constexpr size_t OFF_CUR  = 102039552;    // i32  [16384]
constexpr size_t OFF_COLS = 102105088;    // i32  [E] = 2 MiB
constexpr size_t OFF_NRM  = 104202240;    // f32  [E] = 2 MiB
}

typedef __attribute__((ext_vector_type(8))) short bf16x8;
typedef __attribute__((ext_vector_type(4))) float f32x4;

__device__ __forceinline__ unsigned short f2bf(float f) {
  unsigned int u = __builtin_bit_cast(unsigned int, f);
  u += 0x7fffu + ((u >> 16) & 1u);
  return (unsigned short)(u >> 16);
}
__device__ __forceinline__ float bf2f(unsigned short v) {
  unsigned int u = ((unsigned int)v) << 16;
  return __builtin_bit_cast(float, u);
}

// ---- W1 [16384][256] f32  ->  W1T [256][16384] bf16 ----
__global__ __launch_bounds__(256)
void k_w1t(const float* __restrict__ w1, unsigned short* __restrict__ w1t) {
  __shared__ float tile[64][65];
  const int t = threadIdx.x;
  const int kb = blockIdx.x * 64;
  const int nb = blockIdx.y * 64;
  const int r = t >> 6;
  const int c = t & 63;
#pragma unroll
  for (int i = 0; i < 16; ++i)
    tile[i * 4 + r][c] = w1[(size_t)(kb + i * 4 + r) * CH + nb + c];
  __syncthreads();
#pragma unroll
  for (int i = 0; i < 16; ++i)
    w1t[(size_t)(nb + i * 4 + r) * KD + kb + c] = f2bf(tile[c][i * 4 + r]);
}

// ---- degree + in-edge histogram ----
__global__ __launch_bounds__(256)
void k_deg(const int* __restrict__ dst, const float* __restrict__ ew,
           float* __restrict__ deg, int* __restrict__ cnt) {
  const int e = blockIdx.x * 256 + threadIdx.x;
  const int d = dst[e];
  atomicAdd(&deg[d], ew[e]);
  atomicAdd(&cnt[d], 1);
}

// ---- exclusive scan of cnt -> rowp/cursor, plus dinv (single block) ----
__global__ __launch_bounds__(256)
void k_scan(const int* __restrict__ cnt, const float* __restrict__ deg,
            int* __restrict__ rowp, int* __restrict__ curs,
            float* __restrict__ dinv) {
  __shared__ int ps[256];
  const int t = threadIdx.x;
  const int base = t * 64;
  int s = 0;
  for (int j = 0; j < 64; ++j) s += cnt[base + j];
  ps[t] = s;
  for (int j = 0; j < 64; ++j)
    dinv[base + j] = rsqrtf(deg[base + j] + 1.0f);   // +1 = self-loop weight
  __syncthreads();
  int v = s;
  for (int off = 1; off < 256; off <<= 1) {
    int u = (t >= off) ? ps[t - off] : 0;
    __syncthreads();
    v += u;
    ps[t] = v;
    __syncthreads();
  }
  int run = v - s;
  for (int j = 0; j < 64; ++j) {
    int c = cnt[base + j];
    rowp[base + j] = run;
    curs[base + j] = run;
    run += c;
  }
  if (t == 255) rowp[NN] = run;
}

// ---- CSR fill: edge -> (src, norm) bucketed by dst ----
__global__ __launch_bounds__(256)
void k_fill(const int* __restrict__ src, const int* __restrict__ dst,
            const float* __restrict__ ew, const float* __restrict__ dinv,
            int* __restrict__ curs, int* __restrict__ cols, float* __restrict__ nrm) {
  const int e = blockIdx.x * 256 + threadIdx.x;
  const int s = src[e], d = dst[e];
  const int pos = atomicAdd(&curs[d], 1);
  cols[pos] = s;
  nrm[pos] = dinv[s] * ew[e] * dinv[d];
}

// ---- GEMM1: hp[kb][16384][256] = x[:, kb-quarter] @ W1T[kb-quarter] ----
// BM=64 BN=256, outer BK=256 / inner BK=32. Grid 1024 (2 blocks/CU, 80KB LDS).
// A: 16x 1KB-contiguous wave-bursts per outer into regs, cvt->swizzled As.
// B: glds into 3-buffer ring, counted vmcnt (issues AFTER barrier).
__global__ __launch_bounds__(256, 2)
void k_gemm1(const float* __restrict__ x, const unsigned short* __restrict__ w1t,
             float* __restrict__ hp) {
  __shared__ __align__(16) uint8_t smem[81920];   // As 32KB | Bs 3x16KB

  const int tid  = threadIdx.x;
  const int lane = tid & 63;
  const int wave = tid >> 6;

  const int bid  = blockIdx.x;
  const int xcd  = bid & 7;
  const int slot = bid >> 3;                   // 0..127
  const int kb   = xcd >> 1;                   // 0..3, constant per XCD
  const int bm0  = (slot * 2 + (xcd & 1)) * BM;
  const int koff = kb * (KD / KSPLIT);
  const int wn0  = wave * 64;

  // A source: wave w instr i covers row bm0+16w+i, lane l bytes l*16 of the
  // current 1KB (256-float) window -> one DRAM page per instruction.
  const float* aP0 = x + (size_t)(bm0 + 16 * wave) * KD + koff + lane * 4;
  // B source: pre-swizzled per-lane global (R4-proven mapping)
  const int cc = (lane & 3) ^ ((lane >> 3) & 3);
  const unsigned short* bbase =
      w1t + (size_t)(wave * 64 + (lane >> 2)) * KD + koff + cc * 8;

  // fragment-read coords
  const int fr = lane & 15, fg = lane >> 4;
  const int fch = fg ^ ((fr >> 1) & 3);

  f32x4 acc[4][4] = {};
  float4 ar[16];

  auto A16ISSUE = [&](int oo) {
    const float* ap = aP0 + (size_t)oo * 256;
#pragma unroll
    for (int i = 0; i < 16; ++i)
      ar[i] = *reinterpret_cast<const float4*>(ap + (size_t)i * KD);
  };
  auto STOREA = [&]() {
#pragma unroll
    for (int i = 0; i < 16; ++i) {
      const int row = 16 * wave + i;
      const int byte = row * 512 + ((((lane >> 1) ^ (row & 7))) << 4)
                     + ((lane & 1) << 3);
      uint2 p;
      p.x = (unsigned int)f2bf(ar[i].x) | ((unsigned int)f2bf(ar[i].y) << 16);
      p.y = (unsigned int)f2bf(ar[i].z) | ((unsigned int)f2bf(ar[i].w) << 16);
      *reinterpret_cast<uint2*>(smem + byte) = p;
    }
  };
  auto GLOADB = [&](int g, int bufoff) {
    const unsigned short* src = bbase + (size_t)g * 32;
#pragma unroll
    for (int i = 0; i < 4; ++i) {
      __builtin_amdgcn_global_load_lds(
          (const __attribute__((address_space(1))) void*)(src + (size_t)i * 16 * KD),
          (__attribute__((address_space(3))) void*)(smem + BOFF + bufoff
                                                    + (wave * 64 + i * 16) * 64),
          16, 0, 0);
    }
  };

  // ---- prologue: A(o0) -> As; B(0),B(1) in flight ----
  A16ISSUE(0);
  GLOADB(0, 0);
  GLOADB(1, 16384);
  STOREA();                                   // compiler waits A-regs (once)
  asm volatile("s_waitcnt lgkmcnt(0)" ::: "memory");

  int r0 = 0, r1 = 16384, r2 = 32768;         // ring: buffer of (j%3) this outer

  for (int o = 0; o < NOUT; ++o) {
    const bool last = (o == NOUT - 1);
#pragma unroll
    for (int j = 0; j < 8; ++j) {
      // retire B(o,j); keep deeper loads in flight
      if (j == 7) {
        if (last) asm volatile("s_waitcnt vmcnt(0)" ::: "memory");
        else      asm volatile("s_waitcnt vmcnt(20)" ::: "memory");
      } else {
        asm volatile("s_waitcnt vmcnt(4)" ::: "memory");
      }
      __builtin_amdgcn_s_barrier();
      // issues (after barrier: prior readers of the target buffer are done)
      if (j <= 5 || !last) {
        const int wb = (j + 2) % 3;
        GLOADB(o * 8 + j + 2, wb == 0 ? r0 : (wb == 1 ? r1 : r2));
      }
      if (j == 6 && !last) A16ISSUE(o + 1);
      // fragments
      const int rc = j % 3;
      const uint8_t* Bb = smem + BOFF + (rc == 0 ? r0 : (rc == 1 ? r1 : r2));
      bf16x8 bfr[4], af[4];
#pragma unroll
      for (int ni = 0; ni < 4; ++ni)
        bfr[ni] = *reinterpret_cast<const bf16x8*>(
            Bb + (wn0 + ni * 16 + fr) * 64 + fch * 16);
#pragma unroll
      for (int mi = 0; mi < 4; ++mi)
        af[mi] = *reinterpret_cast<const bf16x8*>(
            smem + (mi * 16 + fr) * 512 + (((j * 4 + fg) ^ (fr & 7)) << 4));
      __builtin_amdgcn_s_setprio(1);
#pragma unroll
      for (int mi = 0; mi < 4; ++mi)
#pragma unroll
        for (int ni = 0; ni < 4; ++ni)
          acc[mi][ni] = __builtin_amdgcn_mfma_f32_16x16x32_bf16(
              af[mi], bfr[ni], acc[mi][ni], 0, 0, 0);
      __builtin_amdgcn_s_setprio(0);
    }
    // outer boundary: refill As for o+1
    __builtin_amdgcn_s_barrier();
    if (!last) {
      STOREA();                               // compiler waits A-regs (covered)
      asm volatile("s_waitcnt lgkmcnt(0)" ::: "memory");
    }
    const int tmp = r2; r2 = r1; r1 = r0; r0 = tmp;   // ring rotate (8 % 3 == 2)
  }

  float* hpo = hp + (size_t)kb * NN * CH;
#pragma unroll
  for (int mi = 0; mi < 4; ++mi)
#pragma unroll
    for (int ni = 0; ni < 4; ++ni)
#pragma unroll
      for (int r = 0; r < 4; ++r) {
        const int m = bm0 + mi * 16 + fg * 4 + r;
        const int n = wn0 + ni * 16 + fr;
        hpo[(size_t)m * CH + n] = acc[mi][ni][r];
      }
}

// ---- reduce 4 partials -> h bf16 ----
__global__ __launch_bounds__(256)
void k_hred(const float* __restrict__ hp, unsigned short* __restrict__ hb) {
  const size_t i = ((size_t)blockIdx.x * 256 + threadIdx.x) * 8;
  float s[8];
#pragma unroll
  for (int j = 0; j < 8; ++j) s[j] = 0.f;
#pragma unroll
  for (int p = 0; p < KSPLIT; ++p) {
    const float* q = hp + (size_t)p * NN * CH + i;
    const float4 v0 = *reinterpret_cast<const float4*>(q);
    const float4 v1 = *reinterpret_cast<const float4*>(q + 4);
    s[0] += v0.x; s[1] += v0.y; s[2] += v0.z; s[3] += v0.w;
    s[4] += v1.x; s[5] += v1.y; s[6] += v1.z; s[7] += v1.w;
  }
  bf16x8 o;
#pragma unroll
  for (int j = 0; j < 8; ++j) o[j] = (short)f2bf(s[j]);
  *reinterpret_cast<bf16x8*>(hb + i) = o;
}

// ---- aggregation 1 (+b1, relu): wave-parallel edges, lane owns 4 channels ----
__global__ __launch_bounds__(256)
void k_agg1(const unsigned short* __restrict__ hb, const int* __restrict__ rowp,
            const int* __restrict__ cols, const float* __restrict__ nrm,
            const float* __restrict__ dinv, const float* __restrict__ b1,
            float* __restrict__ out1) {
  __shared__ float red[4][256];
  const int i = blockIdx.x;
  const int t = threadIdx.x;
  const int w = t >> 6, l = t & 63;
  const int beg = rowp[i], end = rowp[i + 1];
  float a0 = 0.f, a1 = 0.f, a2 = 0.f, a3 = 0.f;
  int e = beg + w;
  for (; e + 4 < end; e += 8) {
    const int s0 = cols[e], s1 = cols[e + 4];
    const float n0 = nrm[e], n1 = nrm[e + 4];
    const ushort4 h0 = *reinterpret_cast<const ushort4*>(hb + (size_t)s0 * CH + l * 4);
    const ushort4 h1 = *reinterpret_cast<const ushort4*>(hb + (size_t)s1 * CH + l * 4);
    a0 += n0 * bf2f(h0.x) + n1 * bf2f(h1.x);
    a1 += n0 * bf2f(h0.y) + n1 * bf2f(h1.y);
    a2 += n0 * bf2f(h0.z) + n1 * bf2f(h1.z);
    a3 += n0 * bf2f(h0.w) + n1 * bf2f(h1.w);
  }
  if (e < end) {
    const int s0 = cols[e];
    const float n0 = nrm[e];
    const ushort4 h0 = *reinterpret_cast<const ushort4*>(hb + (size_t)s0 * CH + l * 4);
    a0 += n0 * bf2f(h0.x); a1 += n0 * bf2f(h0.y);
    a2 += n0 * bf2f(h0.z); a3 += n0 * bf2f(h0.w);
  }
  *reinterpret_cast<float4*>(&red[w][l * 4]) = make_float4(a0, a1, a2, a3);
  __syncthreads();
  const float di = dinv[i];
  float sum = red[0][t] + red[1][t] + red[2][t] + red[3][t]
            + di * di * bf2f(hb[(size_t)i * CH + t]) + b1[t];
  out1[(size_t)i * CH + t] = fmaxf(sum, 0.0f);
}

// ---- GEMM2: h2[16384][16] = out1 @ W2[256][16] ----
__global__ __launch_bounds__(256)
void k_gemm2(const float* __restrict__ out1, const float* __restrict__ w2,
             float* __restrict__ h2) {
  __shared__ float xs[16][256];
  __shared__ float ws[256 * 16];
  const int t = threadIdx.x;
  const int n0 = blockIdx.x * 16;
#pragma unroll
  for (int i = 0; i < 16; ++i) ws[i * 256 + t] = w2[i * 256 + t];
#pragma unroll
  for (int i = 0; i < 16; ++i) xs[i][t] = out1[(size_t)(n0 + i) * CH + t];
  __syncthreads();
  const int node = t >> 4, k = t & 15;
  float acc = 0.f;
#pragma unroll 8
  for (int c = 0; c < 256; ++c) acc += xs[node][c] * ws[c * 16 + k];
  h2[(size_t)(n0 + node) * KC + k] = acc;
}

// ---- aggregation 2 (+b2): one wave per node ----
__global__ __launch_bounds__(256)
void k_agg2(const float* __restrict__ h2, const int* __restrict__ rowp,
            const int* __restrict__ cols, const float* __restrict__ nrm,
            const float* __restrict__ dinv, const float* __restrict__ b2,
            float* __restrict__ out) {
  const int i = blockIdx.x * 4 + (threadIdx.x >> 6);
  const int lane = threadIdx.x & 63;
  const int k = lane & 15, g = lane >> 4;
  const int beg = rowp[i], end = rowp[i + 1];
  float acc = 0.f;
  for (int e = beg + g; e < end; e += 4)
    acc += nrm[e] * h2[(size_t)cols[e] * KC + k];
  acc += __shfl_xor(acc, 16);
  acc += __shfl_xor(acc, 32);
  if (g == 0) {
    const float di = dinv[i];
    out[(size_t)i * KC + k] = acc + di * di * h2[(size_t)i * KC + k] + b2[k];
  }
}

extern "C" void kernel_launch(void* const* d_in, const int* in_sizes, int n_in,
                              void* d_out, int out_size, void* d_ws, size_t ws_size,
                              hipStream_t stream) {
  const float* x  = (const float*)d_in[0];
  const int*   ei = (const int*)d_in[1];
  const float* ew = (const float*)d_in[2];
  const float* w1 = (const float*)d_in[3];
  const float* b1 = (const float*)d_in[4];
  const float* w2 = (const float*)d_in[5];
  const float* b2 = (const float*)d_in[6];
  const int* src = ei;
  const int* dst = ei + NE;

  uint8_t* ws = (uint8_t*)d_ws;
  unsigned short* w1t = (unsigned short*)(ws + OFF_W1T);
  float* hp   = (float*)(ws + OFF_HP);
  unsigned short* hb = (unsigned short*)(ws + OFF_HB);
  float* out1 = (float*)(ws + OFF_OUT1);
  float* h2   = (float*)(ws + OFF_H2);
  float* deg  = (float*)(ws + OFF_DEG);
  int*   cnt  = (int*)(ws + OFF_CNT);
  float* dinv = (float*)(ws + OFF_DINV);
  int*   rowp = (int*)(ws + OFF_ROWP);
  int*   curs = (int*)(ws + OFF_CUR);
  int*   cols = (int*)(ws + OFF_COLS);
  float* nrm  = (float*)(ws + OFF_NRM);
  float* out  = (float*)d_out;

  hipMemsetAsync(ws + OFF_DEG, 0, 131072, stream);  // deg + cnt

  k_w1t <<<dim3(256, 4), 256, 0, stream>>>(w1, w1t);
  k_deg <<<NE / 256, 256, 0, stream>>>(dst, ew, deg, cnt);
  k_scan<<<1, 256, 0, stream>>>(cnt, deg, rowp, curs, dinv);
  k_fill<<<NE / 256, 256, 0, stream>>>(src, dst, ew, dinv, curs, cols, nrm);
  k_gemm1<<<(NN / BM) * KSPLIT, 256, 0, stream>>>(x, w1t, hp);
  k_hred<<<NN * CH / (256 * 8), 256, 0, stream>>>(hp, hb);
  k_agg1<<<NN, 256, 0, stream>>>(hb, rowp, cols, nrm, dinv, b1, out1);
  k_gemm2<<<NN / 16, 256, 0, stream>>>(out1, w2, h2);
  k_agg2<<<NN / 4, 256, 0, stream>>>(h2, rowp, cols, nrm, dinv, b2, out);
}